// Round 2
// baseline (275.219 us; speedup 1.0000x reference)
//
#include <hip/hip_runtime.h>
#include <cstdint>
#include <cstddef>

#define DI __device__ __forceinline__

using f32x4  = __attribute__((ext_vector_type(4))) float;
using bf16x8 = __attribute__((ext_vector_type(8))) short;
using u32x4  = __attribute__((ext_vector_type(4))) unsigned int;

constexpr int NT = 16384;   // tokens
constexpr int NF = 4096;    // features

// fp32 -> bf16 round-to-nearest-even
DI unsigned short f2bf(float f) {
  union { float f; unsigned u; } v; v.f = f;
  unsigned u = v.u;
  u += 0x7fffu + ((u >> 16) & 1u);
  return (unsigned short)(u >> 16);
}

// async global->LDS, 16B per lane. lds dst must be wave-uniform base; HW adds lane*16.
DI void gload_lds16(const void* g, void* l) {
  __builtin_amdgcn_global_load_lds(
      (const __attribute__((address_space(1))) unsigned int*)g,
      (__attribute__((address_space(3))) unsigned int*)l, 16, 0, 0);
}

// ---------------- prep: factor transpose + bf16 cast ----------------
// f0 [b][c][d] f32 -> f0s [d][b][c] bf16 ; f1 [a][b][c] f32 -> f1s same layout bf16
__global__ void ks_prep(const float* __restrict__ f0, const float* __restrict__ f1,
                        unsigned short* __restrict__ f0s, unsigned short* __restrict__ f1s) {
  int tid = blockIdx.x * 256 + threadIdx.x;     // grid covers 2*262144
  if (tid < 262144) {
    int d = tid & 63, c = (tid >> 6) & 63, b = tid >> 12;
    f0s[d * 4096 + b * 64 + c] = f2bf(f0[tid]);
  } else {
    int t2 = tid - 262144;
    f1s[t2] = f2bf(f1[t2]);
  }
}

// ---------------- stage 1 ----------------
// block: 16 tokens x 16 d-slices. y[t][b*64+d] = sum_c x[t][c*64+d]*f0[b][c][d]
__global__ __launch_bounds__(256, 3) void ks_stage1(
    const float* __restrict__ x, const unsigned short* __restrict__ f0s,
    unsigned short* __restrict__ y)
{
  // X tile: [16 d][16 t][64 c] bf16, 128B rows, XOR-swizzled (T2) = 32 KB
  __shared__ __align__(16) char Xb[32768];

  const int bid = blockIdx.x;
  const int dg  = bid & 3;                 // d-group (16 d's)
  const long tt = bid >> 2;                // token tile (16 tokens)
  const int d0  = dg << 4;
  const long t0 = tt << 4;

  const int tid = threadIdx.x;
  const int lane = tid & 63, wv = tid >> 6;     // 4 waves
  const int l15 = lane & 15, lq = lane >> 4;

  // ---- stage x -> LDS (bf16, swizzled). items: (t,c,dq) ; wave reads 1KB contiguous ----
  #pragma unroll
  for (int r = 0; r < 16; ++r) {
    int id = tid + 256 * r;
    int t = id >> 8, c = (id >> 2) & 63, dq = id & 3;
    f32x4 v = *(const f32x4*)(x + (t0 + t) * (long)NF + c * 64 + d0 + dq * 4);
    int sw = (t & 7) << 4;
    #pragma unroll
    for (int j = 0; j < 4; ++j) {
      int delta = dq * 4 + j;
      *(unsigned short*)(Xb + delta * 2048 + t * 128 + ((c * 2) ^ sw)) = f2bf(v[j]);
    }
  }
  __syncthreads();

  const int brow = wv * 16 + l15;          // this wave's b rows (B operand / D cols)
  const int swt  = (l15 & 7) << 4;         // A-row swizzle (row = l15)

  f32x4 acc[16];
  #pragma unroll
  for (int d = 0; d < 16; ++d) acc[d] = (f32x4){0.f, 0.f, 0.f, 0.f};

  #pragma unroll
  for (int d = 0; d < 16; ++d) {
    const char* Xs = Xb + d * 2048 + l15 * 128;
    const unsigned short* Fs = f0s + (size_t)(d0 + d) * 4096 + (size_t)brow * 64;
    #pragma unroll
    for (int k = 0; k < 2; ++k) {
      bf16x8 a = *(const bf16x8*)(Xs + ((k * 64 + lq * 16) ^ swt));     // A[t][c] from LDS
      bf16x8 b = *(const bf16x8*)(Fs + k * 32 + lq * 8);                // B[b][c] direct from L2
      acc[d] = __builtin_amdgcn_mfma_f32_16x16x32_bf16(a, b, acc[d], 0, 0, 0);
    }
  }

  // ---- epilogue: lane holds y[t][brow][d0..d0+15] -> packed 32B coalesced store ----
  #pragma unroll
  for (int i = 0; i < 4; ++i) {
    int t = lq * 4 + i;                    // C/D: col=l15, row=lq*4+i (m89/m91)
    unsigned short h[16];
    #pragma unroll
    for (int d = 0; d < 16; ++d) h[d] = f2bf(acc[d][i]);
    u32x4 w0, w1;
    #pragma unroll
    for (int q = 0; q < 4; ++q) {
      w0[q] = (unsigned)h[2 * q]     | ((unsigned)h[2 * q + 1] << 16);
      w1[q] = (unsigned)h[8 + 2 * q] | ((unsigned)h[9 + 2 * q] << 16);
    }
    unsigned short* yp = y + (t0 + t) * (size_t)NF + (size_t)brow * 64 + d0;
    *(u32x4*)yp = w0;
    *(u32x4*)(yp + 8) = w1;
  }
}

// ---------------- stage 2 ----------------
// block: 32 tokens x 4 a-slices. z[t][a*64+b2] = sum_c y[t][a*64+c]*f1[a][b2][c] + bias
__global__ __launch_bounds__(256, 4) void ks_stage2(
    const unsigned short* __restrict__ y, const unsigned short* __restrict__ f1s,
    const float* __restrict__ bias, float* __restrict__ out)
{
  // Y tile: [4 a][32 t][64 c] bf16 = 16 KB, swizzled via pre-swizzled gload source (m173)
  __shared__ __align__(16) char Yb[16384];

  const int bid = blockIdx.x;
  const int ag  = bid & 15;                // a-group (4 a's)
  const long tt = bid >> 4;                // token tile (32 tokens)
  const int a0  = ag << 2;
  const long t0 = tt << 5;

  const int tid = threadIdx.x;
  const int lane = tid & 63, wv = tid >> 6;
  const int l15 = lane & 15, lq = lane >> 4;

  // stage Y: wave wv loads slice a0+wv; linear LDS dest, inverse-swizzled global src
  #pragma unroll
  for (int q = 0; q < 4; ++q) {
    int pos = q * 1024 + lane * 16;
    int t = pos >> 7, s = (pos >> 4) & 7;
    const char* src = (const char*)y + (t0 + t) * 8192 + (size_t)(a0 + wv) * 128
                      + ((s ^ (t & 7)) << 4);
    gload_lds16(src, Yb + wv * 4096 + q * 1024);
  }
  asm volatile("s_waitcnt vmcnt(0)" ::: "memory");
  __syncthreads();

  const int brow = wv * 16 + l15;
  const int swt  = (l15 & 7) << 4;

  #pragma unroll
  for (int as = 0; as < 4; ++as) {
    int a = a0 + as;
    float bv = bias[a * 64 + brow];
    const unsigned short* Fs = f1s + (size_t)a * 4096 + (size_t)brow * 64;
    bf16x8 b0 = *(const bf16x8*)(Fs + lq * 8);        // B[b][c], k-group offset (FIX)
    bf16x8 b1 = *(const bf16x8*)(Fs + 32 + lq * 8);   // (FIX)
    #pragma unroll
    for (int t2 = 0; t2 < 2; ++t2) {
      const char* Ys = Yb + as * 4096 + (t2 * 16 + l15) * 128;
      f32x4 acc = (f32x4){0.f, 0.f, 0.f, 0.f};
      bf16x8 a0v = *(const bf16x8*)(Ys + ((0  + lq * 16) ^ swt));
      bf16x8 a1v = *(const bf16x8*)(Ys + ((64 + lq * 16) ^ swt));
      acc = __builtin_amdgcn_mfma_f32_16x16x32_bf16(a0v, b0, acc, 0, 0, 0);
      acc = __builtin_amdgcn_mfma_f32_16x16x32_bf16(a1v, b1, acc, 0, 0, 0);
      float* op = out + (t0 + t2 * 16 + lq * 4) * (size_t)NF + (size_t)a * 64 + brow;
      #pragma unroll
      for (int i = 0; i < 4; ++i) op[(size_t)i * NF] = acc[i] + bv;
    }
  }
}

// ---------------- naive fp32 fallback (only if workspace too small) ----------------
__global__ void ks_naive(const float* __restrict__ x, const float* __restrict__ f0,
                         const float* __restrict__ f1, const float* __restrict__ bias,
                         float* __restrict__ out)
{
  __shared__ float xr[4096];
  __shared__ float yr[4096];
  long t = blockIdx.x;
  int tid = threadIdx.x;
  for (int i = tid; i < 4096; i += 256) xr[i] = x[t * 4096 + i];
  __syncthreads();
  for (int i = tid; i < 4096; i += 256) {
    int b = i >> 6, d = i & 63;
    float s = 0.f;
    for (int c = 0; c < 64; ++c) s += xr[c * 64 + d] * f0[(b * 64 + c) * 64 + d];
    yr[i] = s;
  }
  __syncthreads();
  for (int i = tid; i < 4096; i += 256) {
    int a = i >> 6;
    float s = bias[i];
    for (int c = 0; c < 64; ++c) s += yr[a * 64 + c] * f1[(size_t)i * 64 + c];
    out[t * 4096 + i] = s;
  }
}

extern "C" void kernel_launch(void* const* d_in, const int* in_sizes, int n_in,
                              void* d_out, int out_size, void* d_ws, size_t ws_size,
                              hipStream_t stream) {
  const float* x    = (const float*)d_in[0];
  const float* f0   = (const float*)d_in[1];
  const float* f1   = (const float*)d_in[2];
  const float* bias = (const float*)d_in[3];
  float* out = (float*)d_out;

  const size_t ybytes = (size_t)NT * NF * 2;          // 128 MB bf16 intermediate
  const size_t fbytes = (size_t)64 * 64 * 64 * 2;     // 512 KB per factor
  if (ws_size >= ybytes + 2 * fbytes) {
    unsigned short* yw  = (unsigned short*)d_ws;
    unsigned short* f0s = yw + (size_t)NT * NF;
    unsigned short* f1s = f0s + 64 * 64 * 64;
    ks_prep<<<2048, 256, 0, stream>>>(f0, f1, f0s, f1s);
    ks_stage1<<<(NT / 16) * 4, 256, 0, stream>>>(x, f0s, yw);
    ks_stage2<<<(NT / 32) * 16, 256, 0, stream>>>(yw, f1s, bias, out);
  } else {
    ks_naive<<<NT, 256, 0, stream>>>(x, f0, f1, bias, out);
  }
}